// Round 7
// baseline (320.042 us; speedup 1.0000x reference)
//
#include <hip/hip_runtime.h>
#include <hip/hip_bf16.h>
#include <math.h>

#define NT   16384
#define DM   1024
#define NSEG 4
#define BK   64
#define HS   1024
#define TBLN 68
#define GGU  (8 * TBLN)   // k_gateup grid = 544

typedef __attribute__((ext_vector_type(8))) short bf16x8;
typedef __attribute__((ext_vector_type(4))) float f32x4;

typedef __attribute__((address_space(1))) unsigned int gu32;
typedef __attribute__((address_space(3))) unsigned int lu32;

__device__ __forceinline__ void gll16(const void* g, void* l) {
  __builtin_amdgcn_global_load_lds((gu32*)(unsigned long long)g,
                                   (lu32*)(unsigned int)(unsigned long long)l,
                                   16, 0, 0);
}

__device__ __forceinline__ unsigned short cvt_bf16(float f) {
  unsigned int u = __float_as_uint(f);
  u += 0x7fffu + ((u >> 16) & 1u);   // RNE
  return (unsigned short)(u >> 16);
}

// K0: 64-block scan (dtype detect + per-chunk seg counts).
__global__ __launch_bounds__(256) void k_scan(
    const int* __restrict__ idx, int* __restrict__ part) {
  __shared__ int sc[5];
  const int bid = blockIdx.x, tid = threadIdx.x;
  if (tid < 5) sc[tid] = 0;
  __syncthreads();
  int lane = tid & 63;
  int w32 = idx[bid * 256 + tid];               // in bounds for both dtypes
  unsigned long long m = __ballot((tid & 1) && (w32 != 0));
  if (lane == 0 && m) atomicAdd(&sc[4], 1);     // odd word nonzero => int32
  __syncthreads();
  int is32 = (sc[4] != 0);
  int s = w32;
  if (!is32) s = idx[bid * 512 + 2 * tid];      // only if genuinely int64
#pragma unroll
  for (int q = 0; q < 4; ++q) {
    m = __ballot(s == q);
    if (lane == 0 && m) atomicAdd(&sc[q], (int)__popcll(m));
  }
  __syncthreads();
  if (tid < 4) part[bid * 8 + tid] = sc[tid];
  if (tid == 4) part[bid * 8 + 4] = is32;
}

// K1 merged: blocks [0,2048) = rank + x compaction; [2048,5120) = weight
// transposes (independent of part => overlaps with the rank work).
__global__ __launch_bounds__(256) void k_prep(
    const int* __restrict__ idx, const int* __restrict__ part,
    const float4* __restrict__ x,
    int* __restrict__ meta, int2* __restrict__ table,
    int* __restrict__ perm, uint4* __restrict__ xc,
    const float* __restrict__ gw, const float* __restrict__ uw, const float* __restrict__ dw,
    unsigned short* __restrict__ gwt, unsigned short* __restrict__ uwt,
    unsigned short* __restrict__ dwt) {
  __shared__ float tile[64][65];
  __shared__ int cnt[64][4];
  __shared__ int wsum[4][4];
  __shared__ int tot[4], pref[4], gbase[4];
  __shared__ int rnk8[8];
  __shared__ int flag_s;
  const int tid = threadIdx.x;
  if (blockIdx.x >= 2048) {                       // ---- transpose role ----
    int tb = blockIdx.x - 2048;                   // 0..3071
    int mtx = tb >> 10, seg = (tb >> 8) & 3, tl = tb & 255;
    const float* src = (mtx == 0 ? gw : mtx == 1 ? uw : dw) + (size_t)seg * DM * HS;
    unsigned short* dst = (mtx == 0 ? gwt : mtx == 1 ? uwt : dwt) + (size_t)seg * DM * HS;
    int n0 = (tl & 15) * 64, k0 = (tl >> 4) * 64;
    int col = tid & 63, rb = tid >> 6;
#pragma unroll
    for (int i = 0; i < 64; i += 4)
      tile[i + rb][col] = src[(size_t)(k0 + i + rb) * 1024 + n0 + col];
    __syncthreads();
    int kp = tid & 31, nb = tid >> 5;
#pragma unroll
    for (int j = 0; j < 64; j += 8) {
      int nn = j + nb;
      unsigned int w = (unsigned)cvt_bf16(tile[2 * kp][nn]) |
                       ((unsigned)cvt_bf16(tile[2 * kp + 1][nn]) << 16);
      *(unsigned int*)(dst + (size_t)(n0 + nn) * 1024 + k0 + 2 * kp) = w;
    }
    return;
  }
  // ---- rank + compaction role ----
  const int bid = blockIdx.x;
  const int lane = tid & 63, wv = tid >> 6;
  const int c = bid >> 5;                 // chunk 0..63
  const int p0 = (bid & 31) * 8;          // target window within chunk

  if (tid == 0) flag_s = part[c * 8 + 4];
  if (wv == 0) {
#pragma unroll
    for (int s = 0; s < 4; ++s) cnt[lane][s] = part[lane * 8 + s];
  }
  __syncthreads();
  const int is32 = flag_s;
  int tok = c * 256 + tid;
  int s_t = is32 ? idx[tok] : idx[2 * tok];
  int myr = 0;
  unsigned long long lt = (1ull << lane) - 1;
#pragma unroll
  for (int q = 0; q < 4; ++q) {
    unsigned long long m = __ballot(s_t == q);
    if (lane == 0) wsum[wv][q] = (int)__popcll(m);
    if (s_t == q) myr = (int)__popcll(m & lt);
  }
  __syncthreads();
  if (tid < 4) {
    int s = tid, t = 0, p = 0;
    for (int b = 0; b < 64; ++b) { if (b == c) p = t; t += cnt[b][s]; }
    tot[s] = t; pref[s] = p;
  }
  __syncthreads();
  if (tid == 0) {
    gbase[0] = 0;
    for (int s = 1; s < 4; ++s) gbase[s] = gbase[s - 1] + tot[s - 1];
    if (bid == 0) {
      int nt = 0;
      for (int s = 0; s < 4; ++s) {
        meta[s] = tot[s]; meta[5 + s] = gbase[s];
        for (int m0 = 0; m0 < tot[s]; m0 += 256) table[nt++] = make_int2(s, m0);
      }
      for (; nt < TBLN; ++nt) table[nt] = make_int2(-1, 0);
    }
  }
  __syncthreads();
  int wpre = 0;
  for (int w2 = 0; w2 < wv; ++w2) wpre += wsum[w2][s_t];
  int r = gbase[s_t] + pref[s_t] + wpre + myr;
  if (tid >= p0 && tid < p0 + 8) {
    perm[r] = tok;
    rnk8[tid - p0] = r;
  }
  __syncthreads();
  // convert 8 tokens: 32 lanes per token, 1024 f32 each
  const int j = tid >> 5, l2 = tid & 31;
  const int tok8 = bid * 8 + j;
  const float4* src = x + (size_t)tok8 * 256;
  uint4* dst = xc + (size_t)rnk8[j] * 128;
#pragma unroll
  for (int it = 0; it < 4; ++it) {
    float4 a = src[it * 64 + l2 * 2];
    float4 b = src[it * 64 + l2 * 2 + 1];
    uint4 o;
    o.x = cvt_bf16(a.x) | ((unsigned)cvt_bf16(a.y) << 16);
    o.y = cvt_bf16(a.z) | ((unsigned)cvt_bf16(a.w) << 16);
    o.z = cvt_bf16(b.x) | ((unsigned)cvt_bf16(b.y) << 16);
    o.w = cvt_bf16(b.z) | ((unsigned)cvt_bf16(b.w) << 16);
    dst[it * 32 + l2] = o;
  }
}

// ---------------- shared helpers ----------------
#define WAITBAR_(N) \
  asm volatile("s_waitcnt vmcnt(" #N ") lgkmcnt(0)\n\ts_barrier" ::: "memory")
#define WAITBAR(N) WAITBAR_(N)
#define SBAR() __builtin_amdgcn_s_barrier()
#define LGKM0() asm volatile("s_waitcnt lgkmcnt(0)" ::: "memory")

// k_down helpers (R6 structure, 64-elem rows)
#define LDF(BUF, CUR, RB, F)                                               \
  F[0][0] = *(const bf16x8*)(&BUF[CUR][((RB) + fm) * 64] + x0);            \
  F[0][1] = *(const bf16x8*)(&BUF[CUR][((RB) + fm) * 64] + x1);            \
  F[1][0] = *(const bf16x8*)(&BUF[CUR][((RB) + 16 + fm) * 64] + x0);       \
  F[1][1] = *(const bf16x8*)(&BUF[CUR][((RB) + 16 + fm) * 64] + x1);

#define MM8(ACC, MH, NH, AF, BF)                                                                                            \
  __builtin_amdgcn_s_setprio(1);                                                                                            \
  ACC[2*(MH)+0][2*(NH)+0] = __builtin_amdgcn_mfma_f32_16x16x32_bf16(AF[0][0], BF[0][0], ACC[2*(MH)+0][2*(NH)+0], 0, 0, 0);  \
  ACC[2*(MH)+0][2*(NH)+1] = __builtin_amdgcn_mfma_f32_16x16x32_bf16(AF[0][0], BF[1][0], ACC[2*(MH)+0][2*(NH)+1], 0, 0, 0);  \
  ACC[2*(MH)+1][2*(NH)+0] = __builtin_amdgcn_mfma_f32_16x16x32_bf16(AF[1][0], BF[0][0], ACC[2*(MH)+1][2*(NH)+0], 0, 0, 0);  \
  ACC[2*(MH)+1][2*(NH)+1] = __builtin_amdgcn_mfma_f32_16x16x32_bf16(AF[1][0], BF[1][0], ACC[2*(MH)+1][2*(NH)+1], 0, 0, 0);  \
  ACC[2*(MH)+0][2*(NH)+0] = __builtin_amdgcn_mfma_f32_16x16x32_bf16(AF[0][1], BF[0][1], ACC[2*(MH)+0][2*(NH)+0], 0, 0, 0);  \
  ACC[2*(MH)+0][2*(NH)+1] = __builtin_amdgcn_mfma_f32_16x16x32_bf16(AF[0][1], BF[1][1], ACC[2*(MH)+0][2*(NH)+1], 0, 0, 0);  \
  ACC[2*(MH)+1][2*(NH)+0] = __builtin_amdgcn_mfma_f32_16x16x32_bf16(AF[1][1], BF[0][1], ACC[2*(MH)+1][2*(NH)+0], 0, 0, 0);  \
  ACC[2*(MH)+1][2*(NH)+1] = __builtin_amdgcn_mfma_f32_16x16x32_bf16(AF[1][1], BF[1][1], ACC[2*(MH)+1][2*(NH)+1], 0, 0, 0);  \
  __builtin_amdgcn_s_setprio(0);

// ---------------- GEMM 1: gate+up fused, 256x256 8-phase template ----------------
// BM=256, BN=256 (panel: gate/up interleaved in 16-row blocks), BK=32.
// 8 waves = 2M x 4N; per-wave out 128 x 64 panel cols; 2 phases/tile,
// 16 MFMA per phase under setprio; barriers 4/tile (template density).
// LDS: A 3x16K + B 3x16K = 96 KiB; depth-2 staging, one vmcnt(4)/tile.
// Row-pair XOR layout: byte(pr, j2) = (pr>>1)*128 + ((((pr&1)<<2)|j2)^((pr>>1)&7))*16.
__global__ __launch_bounds__(512) void k_gateup(
    const unsigned short* __restrict__ xc,
    const unsigned short* __restrict__ gwt,
    const unsigned short* __restrict__ uwt,
    const int* __restrict__ meta,
    const int2* __restrict__ table,
    unsigned short* __restrict__ hidden) {
  __shared__ __align__(16) unsigned short As[3][256 * 32];
  __shared__ __align__(16) unsigned short Bs[3][256 * 32];
  const int bid = blockIdx.x, tid = threadIdx.x;
  const int lb = (bid & 7) * (GGU / 8) + (bid >> 3);   // 544 = 8*68 bijective
  const int2 te = table[lb >> 3];
  if (te.x < 0) return;
  const int seg = te.x, m0 = te.y;
  const int count = meta[seg], base = meta[5 + seg];
  const int n0 = (lb & 7) * 128;                       // gate/up col base

  const int lane = tid & 63, wv = tid >> 6;
  const int mi = wv >> 2, ng = wv & 3;                 // 2M x 4N waves
  const int fm = lane & 15, fq = lane >> 4;
  const int laneRd = (fm >> 1) * 128 + (((((fm & 1) << 2) | fq)) ^ (fm >> 1)) * 16;

  // staging slots (2 A + 2 B per thread per tile), pre-swizzled sources
  const unsigned short *aS0, *aS1, *bS0, *bS1;
  int aO0, aO1, bO0, bO1;
  {
    int o0 = wv * 1024 + lane * 16;
    int o1 = 8192 + o0;
    int rp0 = o0 >> 7, jj0 = ((o0 >> 4) & 7) ^ (rp0 & 7);
    int rp1 = o1 >> 7, jj1 = ((o1 >> 4) & 7) ^ (rp1 & 7);
    int pr0 = rp0 * 2 + (jj0 >> 2), j20 = jj0 & 3;
    int pr1 = rp1 * 2 + (jj1 >> 2), j21 = jj1 & 3;
    int ga0 = m0 + pr0; ga0 = ga0 < count ? ga0 : count - 1;
    int ga1 = m0 + pr1; ga1 = ga1 < count ? ga1 : count - 1;
    aS0 = xc + (size_t)(base + ga0) * DM + j20 * 8;  aO0 = o0;
    aS1 = xc + (size_t)(base + ga1) * DM + j21 * 8;  aO1 = o1;
    int nc0 = n0 + (pr0 >> 5) * 16 + (pr0 & 15);
    int nc1 = n0 + (pr1 >> 5) * 16 + (pr1 & 15);
    bS0 = (((pr0 >> 4) & 1) ? uwt : gwt) + (size_t)(seg * HS + nc0) * DM + j20 * 8;  bO0 = o0;
    bS1 = (((pr1 >> 4) & 1) ? uwt : gwt) + (size_t)(seg * HS + nc1) * DM + j21 * 8;  bO1 = o1;
  }

  f32x4 acc[8][4] = {};

#define GU_SA(B) { gll16(aS0, (char*)&As[B][0] + aO0); gll16(aS1, (char*)&As[B][0] + aO1); aS0 += 32; aS1 += 32; }
#define GU_SB(B) { gll16(bS0, (char*)&Bs[B][0] + bO0); gll16(bS1, (char*)&Bs[B][0] + bO1); bS0 += 32; bS1 += 32; }

#define GU_PH1(C, STMT) {                                                   \
    const char* Ab = (const char*)&As[C][0];                                \
    const char* Bb = (const char*)&Bs[C][0];                                \
    _Pragma("unroll")                                                       \
    for (int f = 0; f < 4; ++f)                                             \
      afr[f] = *(const bf16x8*)(Ab + (mi * 128 + f * 16) * 64 + laneRd);    \
    _Pragma("unroll")                                                       \
    for (int f = 0; f < 4; ++f)                                             \
      bfr[f] = *(const bf16x8*)(Bb + (ng * 64 + f * 16) * 64 + laneRd);     \
    STMT;                                                                   \
    SBAR(); LGKM0();                                                        \
    __builtin_amdgcn_s_setprio(1);                                          \
    _Pragma("unroll")                                                       \
    for (int f = 0; f < 4; ++f)                                             \
      _Pragma("unroll")                                                     \
      for (int n = 0; n < 4; ++n)                                           \
        acc[f][n] = __builtin_amdgcn_mfma_f32_16x16x32_bf16(afr[f], bfr[n], acc[f][n], 0, 0, 0); \
    __builtin_amdgcn_s_setprio(0);                                          \
    SBAR(); }

#define GU_PH2(C, STMT, GN) {                                               \
    const char* Ab = (const char*)&As[C][0];                                \
    _Pragma("unroll")                                                       \
    for (int f = 0; f < 4; ++f)                                             \
      afr[f] = *(const bf16x8*)(Ab + (mi * 128 + 64 + f * 16) * 64 + laneRd); \
    STMT;                                                                   \
    SBAR(); LGKM0();                                                        \
    __builtin_amdgcn_s_setprio(1);                                          \
    _Pragma("unroll")                                                       \
    for (int f = 0; f < 4; ++f)                                             \
      _Pragma("unroll")                                                     \
      for (int n = 0; n < 4; ++n)                                           \
        acc[4 + f][n] = __builtin_amdgcn_mfma_f32_16x16x32_bf16(afr[f], bfr[n], acc[4 + f][n], 0, 0, 0); \
    __builtin_amdgcn_s_setprio(0);                                          \
    WAITBAR(GN); }

#define GU_TILE(C, P) { bf16x8 afr[4], bfr[4];                              \
    GU_PH1(C, GU_SA(P)); GU_PH2(C, GU_SB(P), 4); }
#define GU_TILE_E(C, GN) { bf16x8 afr[4], bfr[4];                           \
    GU_PH1(C, ); GU_PH2(C, , GN); }

  // prologue: drain setup loads, stage tiles 0 and 1, gate tile 0
  asm volatile("s_waitcnt vmcnt(0)" ::: "memory");
  GU_SA(0); GU_SB(0);
  GU_SA(1); GU_SB(1);
  WAITBAR(4);                 // tile0's 4 landed; tile1's 4 in flight

#pragma unroll 1
  for (int g3 = 0; g3 < 10; ++g3) {   // tiles 0..29, stage t+2
    GU_TILE(0, 2);
    GU_TILE(1, 0);
    GU_TILE(2, 1);
  }
  GU_TILE_E(0, 0);                    // tile 30 (drain tile31's staging)
  GU_TILE_E(1, 0);                    // tile 31
#undef GU_TILE
#undef GU_TILE_E
#undef GU_PH1
#undef GU_PH2
#undef GU_SA
#undef GU_SB

  // epilogue: frag ni pairs (gate=2q, up=2q+1) share ncol
#pragma unroll
  for (int mf = 0; mf < 8; ++mf) {
#pragma unroll
    for (int r = 0; r < 4; ++r) {
      int row = m0 + mi * 128 + mf * 16 + fq * 4 + r;
      if (row < count) {
        unsigned short* h = hidden + (size_t)(base + row) * HS;
#pragma unroll
        for (int q = 0; q < 2; ++q) {
          int ncol = n0 + (ng * 2 + q) * 16 + fm;
          float gv = acc[mf][2 * q][r];
          float uv = acc[mf][2 * q + 1][r];
          float sig = 1.0f / (1.0f + __expf(-gv));
          h[ncol] = cvt_bf16(gv * sig * uv);
        }
      }
    }
  }
}

// ---------------- GEMM 2: down, scatter rows to out (R6 structure) ----------------
__global__ __launch_bounds__(512) void k_down(
    const unsigned short* __restrict__ hidden,
    const unsigned short* __restrict__ dwt,
    const int* __restrict__ meta,
    const int2* __restrict__ table,
    const int* __restrict__ perm,
    float* __restrict__ out) {
  __shared__ __align__(16) unsigned short As[2][256 * BK];
  __shared__ __align__(16) unsigned short Bs[1][128 * BK];
  const int bid = blockIdx.x, tid = threadIdx.x;
  const int lb = (bid & 7) * (8 * TBLN / 8) + (bid >> 3);
  const int2 te = table[lb >> 3];
  if (te.x < 0) return;
  const int seg = te.x, m0 = te.y;
  const int count = meta[seg], base = meta[5 + seg];
  const int n0 = (lb & 7) * 128;

  const int lane = tid & 63;
  const int wv = tid >> 6;
  const int l0 = lane >> 3, j = lane & 7;

  const int rl0 = wv * 8, rl1 = 64 + wv * 8;
  const int rb0 = (rl0 & 31) + (rl0 >> 5) * 64;
  const int rb1 = (rl1 & 31) + (rl1 >> 5) * 64;
  const int a0d0 = rb0 * 128, a0d1 = rb1 * 128;
  const int a1d0 = a0d0 + 32 * 128, a1d1 = a0d1 + 32 * 128;
  const int r00 = rb0 + l0, r01 = rb1 + l0;
  const int r10 = r00 + 32, r11 = r01 + 32;
  auto rowof = [&](int r) { int g = m0 + r; return g < count ? g : count - 1; };
  const unsigned short* a0p0 = hidden + (size_t)(base + rowof(r00)) * HS + (j ^ (r00 & 7)) * 8;
  const unsigned short* a0p1 = hidden + (size_t)(base + rowof(r01)) * HS + (j ^ (r01 & 7)) * 8;
  const unsigned short* a1p0 = hidden + (size_t)(base + rowof(r10)) * HS + (j ^ (r10 & 7)) * 8;
  const unsigned short* a1p1 = hidden + (size_t)(base + rowof(r11)) * HS + (j ^ (r11 & 7)) * 8;
  const int nl = wv * 8 + l0;
  const int nb0 = (nl & 31) + (nl >> 5) * 64;
  const int nb1 = nb0 + 32;
  const unsigned short* bp0 = dwt + (size_t)(seg * DM + n0 + nb0) * HS + (j ^ (nb0 & 7)) * 8;
  const unsigned short* bp1 = dwt + (size_t)(seg * DM + n0 + nb1) * HS + (j ^ (nb1 & 7)) * 8;
  const int bw = wv * 8;
  const int bd0 = ((bw & 31) + (bw >> 5) * 64) * 128;
  const int bd1 = bd0 + 32 * 128;

  const int wm = (wv & 3) * 64;
  const int wn = (wv >> 2) * 64;
  const int fm = lane & 15, fq = lane >> 4;
  const int x0 = (fq ^ (fm & 7)) * 8;
  const int x1 = ((4 + fq) ^ (fm & 7)) * 8;

  f32x4 acc[4][4] = {};

#define DN_ITER(CUR, NXT) {                                   \
    bf16x8 af[2][2], af2[2][2], b0[2][2], b1[2][2];           \
    gll16(a0p0, (char*)&As[NXT][0] + a0d0);                   \
    gll16(a0p1, (char*)&As[NXT][0] + a0d1);                   \
    WAITBAR(3);                                               \
    LDF(As, CUR, wm, af); LDF(Bs, 0, wn, b0);                 \
    MM8(acc, 0, 0, af, b0);                                   \
    WAITBAR(2);                                               \
    LDF(Bs, 0, wn + 32, b1);                                  \
    MM8(acc, 0, 1, af, b1);                                   \
    WAITBAR(2);                                               \
    LDF(As, CUR, wm + 32, af2);                               \
    gll16(a1p0, (char*)&As[NXT][0] + a1d0);                   \
    gll16(a1p1, (char*)&As[NXT][0] + a1d1);                   \
    gll16(bp0, (char*)&Bs[0][0] + bd0);                       \
    gll16(bp1, (char*)&Bs[0][0] + bd1);                       \
    MM8(acc, 1, 0, af2, b0);                                  \
    MM8(acc, 1, 1, af2, b1);                                  \
    a0p0 += BK; a0p1 += BK; a1p0 += BK; a1p1 += BK; bp0 += BK; bp1 += BK; \
  }

  gll16(a0p0, (char*)&As[0][0] + a0d0);
  gll16(a0p1, (char*)&As[0][0] + a0d1);
  gll16(a1p0, (char*)&As[0][0] + a1d0);
  gll16(a1p1, (char*)&As[0][0] + a1d1);
  gll16(bp0,  (char*)&Bs[0][0] + bd0);
  gll16(bp1,  (char*)&Bs[0][0] + bd1);
  a0p0 += BK; a0p1 += BK; a1p0 += BK; a1p1 += BK; bp0 += BK; bp1 += BK;

#pragma unroll 1
  for (int t7 = 0; t7 < 7; ++t7) {
    DN_ITER(0, 1);
    DN_ITER(1, 0);
  }
  DN_ITER(0, 1);
  {
    bf16x8 af[2][2], af2[2][2], b0[2][2], b1[2][2];
    WAITBAR(1);
    LDF(As, 1, wm, af); LDF(Bs, 0, wn, b0);
    MM8(acc, 0, 0, af, b0);
    WAITBAR(0);
    LDF(Bs, 0, wn + 32, b1);
    MM8(acc, 0, 1, af, b1);
    WAITBAR(0);
    LDF(As, 1, wm + 32, af2);
    MM8(acc, 1, 0, af2, b0);
    MM8(acc, 1, 1, af2, b1);
  }
#undef DN_ITER

  const int rq = fq * 4;
#pragma unroll
  for (int mi = 0; mi < 4; ++mi) {
#pragma unroll
    for (int r = 0; r < 4; ++r) {
      int row = m0 + wm + mi * 16 + rq + r;
      if (row < count) {
        int t = perm[base + row];
        float* o = out + (size_t)t * DM + n0 + wn;
#pragma unroll
        for (int ni = 0; ni < 4; ++ni)
          o[ni * 16 + fm] = acc[mi][ni][r];
      }
    }
  }
}

// ---------------- launch ----------------

extern "C" void kernel_launch(void* const* d_in, const int* in_sizes, int n_in,
                              void* d_out, int out_size, void* d_ws, size_t ws_size,
                              hipStream_t stream) {
  const float* x  = (const float*)d_in[0];
  const float* gw = (const float*)d_in[1];
  const float* uw = (const float*)d_in[2];
  const float* dw = (const float*)d_in[3];
  const int* tsi  = (const int*)d_in[4];
  float* out = (float*)d_out;

  char* ws = (char*)d_ws;
  int*  meta  = (int*)ws;                        // 64 ints
  int*  part  = (int*)(ws + 256);                // 64*8 ints
  int2* table = (int2*)(ws + 4096);              // TBLN entries
  int*  perm  = (int*)(ws + 8192);               // NT ints (64 KiB)
  unsigned short* xc  = (unsigned short*)(ws + (1 << 18));  // 32 MiB compacted
  unsigned short* gwt = xc + (size_t)NT * DM;               // 8 MiB
  unsigned short* uwt = gwt + (size_t)NSEG * HS * DM;       // 8 MiB
  unsigned short* dwt = uwt + (size_t)NSEG * HS * DM;       // 8 MiB
  unsigned short* hid = dwt + (size_t)NSEG * DM * HS;       // 32 MiB compacted

  k_scan<<<64, 256, 0, stream>>>(tsi, part);
  k_prep<<<2048 + 3072, 256, 0, stream>>>(tsi, part, (const float4*)x, meta, table,
                                          perm, (uint4*)xc, gw, uw, dw, gwt, uwt, dwt);
  k_gateup<<<GGU, 512, 0, stream>>>(xc, gwt, uwt, meta, table, hid);
  k_down<<<8 * TBLN, 512, 0, stream>>>(hid, dwt, meta, table, perm, out);
}

// Round 8
// 299.047 us; speedup vs baseline: 1.0702x; 1.0702x over previous
//
#include <hip/hip_runtime.h>
#include <hip/hip_bf16.h>
#include <math.h>

#define NT   16384
#define DM   1024
#define NSEG 4
#define BK   64
#define HS   1024
#define TBLN 68

typedef __attribute__((ext_vector_type(8))) short bf16x8;
typedef __attribute__((ext_vector_type(4))) float f32x4;

typedef __attribute__((address_space(1))) unsigned int gu32;
typedef __attribute__((address_space(3))) unsigned int lu32;

__device__ __forceinline__ void gll16(const void* g, void* l) {
  __builtin_amdgcn_global_load_lds((gu32*)(unsigned long long)g,
                                   (lu32*)(unsigned int)(unsigned long long)l,
                                   16, 0, 0);
}

__device__ __forceinline__ unsigned short cvt_bf16(float f) {
  unsigned int u = __float_as_uint(f);
  u += 0x7fffu + ((u >> 16) & 1u);   // RNE
  return (unsigned short)(u >> 16);
}

// K0: 64-block scan (dtype detect + per-chunk seg counts).
__global__ __launch_bounds__(256) void k_scan(
    const int* __restrict__ idx, int* __restrict__ part) {
  __shared__ int sc[5];
  const int bid = blockIdx.x, tid = threadIdx.x;
  if (tid < 5) sc[tid] = 0;
  __syncthreads();
  int lane = tid & 63;
  int w32 = idx[bid * 256 + tid];               // in bounds for both dtypes
  unsigned long long m = __ballot((tid & 1) && (w32 != 0));
  if (lane == 0 && m) atomicAdd(&sc[4], 1);     // odd word nonzero => int32
  __syncthreads();
  int is32 = (sc[4] != 0);
  int s = w32;
  if (!is32) s = idx[bid * 512 + 2 * tid];      // only if genuinely int64
#pragma unroll
  for (int q = 0; q < 4; ++q) {
    m = __ballot(s == q);
    if (lane == 0 && m) atomicAdd(&sc[q], (int)__popcll(m));
  }
  __syncthreads();
  if (tid < 4) part[bid * 8 + tid] = sc[tid];
  if (tid == 4) part[bid * 8 + 4] = is32;
}

// K1 merged: blocks [0,2048) = rank + x compaction; [2048,5120) = weight
// transposes (independent of part => overlaps with the rank work).
__global__ __launch_bounds__(256) void k_prep(
    const int* __restrict__ idx, const int* __restrict__ part,
    const float4* __restrict__ x,
    int* __restrict__ meta, int2* __restrict__ table,
    int* __restrict__ perm, uint4* __restrict__ xc,
    const float* __restrict__ gw, const float* __restrict__ uw, const float* __restrict__ dw,
    unsigned short* __restrict__ gwt, unsigned short* __restrict__ uwt,
    unsigned short* __restrict__ dwt) {
  __shared__ float tile[64][65];
  __shared__ int cnt[64][4];
  __shared__ int wsum[4][4];
  __shared__ int tot[4], pref[4], gbase[4];
  __shared__ int rnk8[8];
  __shared__ int flag_s;
  const int tid = threadIdx.x;
  if (blockIdx.x >= 2048) {                       // ---- transpose role ----
    int tb = blockIdx.x - 2048;                   // 0..3071
    int mtx = tb >> 10, seg = (tb >> 8) & 3, tl = tb & 255;
    const float* src = (mtx == 0 ? gw : mtx == 1 ? uw : dw) + (size_t)seg * DM * HS;
    unsigned short* dst = (mtx == 0 ? gwt : mtx == 1 ? uwt : dwt) + (size_t)seg * DM * HS;
    int n0 = (tl & 15) * 64, k0 = (tl >> 4) * 64;
    int col = tid & 63, rb = tid >> 6;
#pragma unroll
    for (int i = 0; i < 64; i += 4)
      tile[i + rb][col] = src[(size_t)(k0 + i + rb) * 1024 + n0 + col];
    __syncthreads();
    int kp = tid & 31, nb = tid >> 5;
#pragma unroll
    for (int j = 0; j < 64; j += 8) {
      int nn = j + nb;
      unsigned int w = (unsigned)cvt_bf16(tile[2 * kp][nn]) |
                       ((unsigned)cvt_bf16(tile[2 * kp + 1][nn]) << 16);
      *(unsigned int*)(dst + (size_t)(n0 + nn) * 1024 + k0 + 2 * kp) = w;
    }
    return;
  }
  // ---- rank + compaction role ----
  const int bid = blockIdx.x;
  const int lane = tid & 63, wv = tid >> 6;
  const int c = bid >> 5;                 // chunk 0..63
  const int p0 = (bid & 31) * 8;          // target window within chunk

  if (tid == 0) flag_s = part[c * 8 + 4];
  if (wv == 0) {
#pragma unroll
    for (int s = 0; s < 4; ++s) cnt[lane][s] = part[lane * 8 + s];
  }
  __syncthreads();
  const int is32 = flag_s;
  int tok = c * 256 + tid;
  int s_t = is32 ? idx[tok] : idx[2 * tok];
  int myr = 0;
  unsigned long long lt = (1ull << lane) - 1;
#pragma unroll
  for (int q = 0; q < 4; ++q) {
    unsigned long long m = __ballot(s_t == q);
    if (lane == 0) wsum[wv][q] = (int)__popcll(m);
    if (s_t == q) myr = (int)__popcll(m & lt);
  }
  __syncthreads();
  if (tid < 4) {
    int s = tid, t = 0, p = 0;
    for (int b = 0; b < 64; ++b) { if (b == c) p = t; t += cnt[b][s]; }
    tot[s] = t; pref[s] = p;
  }
  __syncthreads();
  if (tid == 0) {
    gbase[0] = 0;
    for (int s = 1; s < 4; ++s) gbase[s] = gbase[s - 1] + tot[s - 1];
    if (bid == 0) {
      int nt = 0;
      for (int s = 0; s < 4; ++s) {
        meta[s] = tot[s]; meta[5 + s] = gbase[s];
        for (int m0 = 0; m0 < tot[s]; m0 += 256) table[nt++] = make_int2(s, m0);
      }
      for (; nt < TBLN; ++nt) table[nt] = make_int2(-1, 0);
    }
  }
  __syncthreads();
  int wpre = 0;
  for (int w2 = 0; w2 < wv; ++w2) wpre += wsum[w2][s_t];
  int r = gbase[s_t] + pref[s_t] + wpre + myr;
  if (tid >= p0 && tid < p0 + 8) {
    perm[r] = tok;
    rnk8[tid - p0] = r;
  }
  __syncthreads();
  // convert 8 tokens: 32 lanes per token, 1024 f32 each
  const int j = tid >> 5, l2 = tid & 31;
  const int tok8 = bid * 8 + j;
  const float4* src = x + (size_t)tok8 * 256;
  uint4* dst = xc + (size_t)rnk8[j] * 128;
#pragma unroll
  for (int it = 0; it < 4; ++it) {
    float4 a = src[it * 64 + l2 * 2];
    float4 b = src[it * 64 + l2 * 2 + 1];
    uint4 o;
    o.x = cvt_bf16(a.x) | ((unsigned)cvt_bf16(a.y) << 16);
    o.y = cvt_bf16(a.z) | ((unsigned)cvt_bf16(a.w) << 16);
    o.z = cvt_bf16(b.x) | ((unsigned)cvt_bf16(b.y) << 16);
    o.w = cvt_bf16(b.z) | ((unsigned)cvt_bf16(b.w) << 16);
    dst[it * 32 + l2] = o;
  }
}

// ---------------- counted-vmcnt pipeline helpers ----------------
#define WAITBAR_(N) \
  asm volatile("s_waitcnt vmcnt(" #N ") lgkmcnt(0)\n\ts_barrier" ::: "memory")
#define WAITBAR(N) WAITBAR_(N)

// Load a 2x2 fragment block (rows RB+{0,16}+fm, both K-halves) from LDS.
#define LDF(BUF, CUR, RB, F)                                               \
  F[0][0] = *(const bf16x8*)(&BUF[CUR][((RB) + fm) * 64] + x0);            \
  F[0][1] = *(const bf16x8*)(&BUF[CUR][((RB) + fm) * 64] + x1);            \
  F[1][0] = *(const bf16x8*)(&BUF[CUR][((RB) + 16 + fm) * 64] + x0);       \
  F[1][1] = *(const bf16x8*)(&BUF[CUR][((RB) + 16 + fm) * 64] + x1);

// 8 MFMA (2x2 frags x K=64) wrapped in setprio (T5).
#define MM8(ACC, MH, NH, AF, BF)                                                                                            \
  __builtin_amdgcn_s_setprio(1);                                                                                            \
  ACC[2*(MH)+0][2*(NH)+0] = __builtin_amdgcn_mfma_f32_16x16x32_bf16(AF[0][0], BF[0][0], ACC[2*(MH)+0][2*(NH)+0], 0, 0, 0);  \
  ACC[2*(MH)+0][2*(NH)+1] = __builtin_amdgcn_mfma_f32_16x16x32_bf16(AF[0][0], BF[1][0], ACC[2*(MH)+0][2*(NH)+1], 0, 0, 0);  \
  ACC[2*(MH)+1][2*(NH)+0] = __builtin_amdgcn_mfma_f32_16x16x32_bf16(AF[1][0], BF[0][0], ACC[2*(MH)+1][2*(NH)+0], 0, 0, 0);  \
  ACC[2*(MH)+1][2*(NH)+1] = __builtin_amdgcn_mfma_f32_16x16x32_bf16(AF[1][0], BF[1][0], ACC[2*(MH)+1][2*(NH)+1], 0, 0, 0);  \
  ACC[2*(MH)+0][2*(NH)+0] = __builtin_amdgcn_mfma_f32_16x16x32_bf16(AF[0][1], BF[0][1], ACC[2*(MH)+0][2*(NH)+0], 0, 0, 0);  \
  ACC[2*(MH)+0][2*(NH)+1] = __builtin_amdgcn_mfma_f32_16x16x32_bf16(AF[0][1], BF[1][1], ACC[2*(MH)+0][2*(NH)+1], 0, 0, 0);  \
  ACC[2*(MH)+1][2*(NH)+0] = __builtin_amdgcn_mfma_f32_16x16x32_bf16(AF[1][1], BF[0][1], ACC[2*(MH)+1][2*(NH)+0], 0, 0, 0);  \
  ACC[2*(MH)+1][2*(NH)+1] = __builtin_amdgcn_mfma_f32_16x16x32_bf16(AF[1][1], BF[1][1], ACC[2*(MH)+1][2*(NH)+1], 0, 0, 0);  \
  __builtin_amdgcn_s_setprio(0);

// ---------------- GEMM 1 (R6-best): gate+up fused, silu epilogue ----------------
// BM=256, N = 64 gate + 64 up, BK=64, 512 thr (8 waves, 4M x 2N).
// LDS = 80 KiB: A dbuf (64K), Bg/Bu single (8K+8K). Waits 5/2/3; epi 3/0/0.
__global__ __launch_bounds__(512) void k_gateup(
    const unsigned short* __restrict__ xc,
    const unsigned short* __restrict__ gwt,
    const unsigned short* __restrict__ uwt,
    const int* __restrict__ meta,
    const int2* __restrict__ table,
    unsigned short* __restrict__ hidden) {
  __shared__ __align__(16) unsigned short As[2][256 * BK];
  __shared__ __align__(16) unsigned short Bg[1][64 * BK];
  __shared__ __align__(16) unsigned short Bu[1][64 * BK];
  const int bid = blockIdx.x, tid = threadIdx.x;
  // XCD-aware swizzle: grid = 16*TBLN = 1088 = 8*136 (bijective)
  const int lb = (bid & 7) * (16 * TBLN / 8) + (bid >> 3);
  const int2 te = table[lb >> 4];
  if (te.x < 0) return;
  const int seg = te.x, m0 = te.y;
  const int count = meta[seg], base = meta[5 + seg];
  const int n0 = (lb & 15) * 64;

  const int lane = tid & 63;
  const int wv = tid >> 6;
  const int l0 = lane >> 3, j = lane & 7;

  const int rl0 = wv * 8, rl1 = 64 + wv * 8;
  const int rb0 = (rl0 & 31) + (rl0 >> 5) * 64;
  const int rb1 = (rl1 & 31) + (rl1 >> 5) * 64;
  const int a0d0 = rb0 * 128, a0d1 = rb1 * 128;
  const int a1d0 = a0d0 + 32 * 128, a1d1 = a0d1 + 32 * 128;
  const int r00 = rb0 + l0, r01 = rb1 + l0;
  const int r10 = r00 + 32, r11 = r01 + 32;
  auto rowof = [&](int r) { int g = m0 + r; return g < count ? g : count - 1; };
  const unsigned short* a0p0 = xc + (size_t)(base + rowof(r00)) * DM + (j ^ (r00 & 7)) * 8;
  const unsigned short* a0p1 = xc + (size_t)(base + rowof(r01)) * DM + (j ^ (r01 & 7)) * 8;
  const unsigned short* a1p0 = xc + (size_t)(base + rowof(r10)) * DM + (j ^ (r10 & 7)) * 8;
  const unsigned short* a1p1 = xc + (size_t)(base + rowof(r11)) * DM + (j ^ (r11 & 7)) * 8;
  const int nb = wv * 8 + l0;                        // 0..63
  const unsigned short* gp  = gwt + (size_t)(seg * HS + n0 + nb) * DM + (j ^ (nb & 7)) * 8;
  const unsigned short* upp = uwt + (size_t)(seg * HS + n0 + nb) * DM + (j ^ (nb & 7)) * 8;
  const int bd = wv * 1024;

  const int wm = (wv & 3) * 64;          // 4 M-waves
  const int wn = (wv >> 2) * 32;         // 2 N-waves
  const int fm = lane & 15, fq = lane >> 4;
  const int x0 = (fq ^ (fm & 7)) * 8;
  const int x1 = ((4 + fq) ^ (fm & 7)) * 8;

  f32x4 accg[4][2] = {};
  f32x4 accu[4][2] = {};

#define GU_ITER(CUR, NXT) {                                   \
    bf16x8 af[2][2], af2[2][2], bg2[2][2], bu2[2][2];         \
    gll16(a0p0, (char*)&As[NXT][0] + a0d0);                   \
    gll16(a0p1, (char*)&As[NXT][0] + a0d1);                   \
    WAITBAR(5);                                               \
    LDF(As, CUR, wm, af); LDF(Bg, 0, wn, bg2);                \
    MM8(accg, 0, 0, af, bg2);                                 \
    WAITBAR(2);                                               \
    LDF(Bu, 0, wn, bu2);                                      \
    gll16(gp, (char*)&Bg[0][0] + bd);                         \
    MM8(accu, 0, 0, af, bu2);                                 \
    WAITBAR(3);                                               \
    LDF(As, CUR, wm + 32, af2);                               \
    gll16(a1p0, (char*)&As[NXT][0] + a1d0);                   \
    gll16(a1p1, (char*)&As[NXT][0] + a1d1);                   \
    gll16(upp, (char*)&Bu[0][0] + bd);                        \
    MM8(accg, 1, 0, af2, bg2);                                \
    MM8(accu, 1, 0, af2, bu2);                                \
    a0p0 += BK; a0p1 += BK; a1p0 += BK; a1p1 += BK; gp += BK; upp += BK; \
  }

  // prologue: stage tile 0 in steady-state slot order a0,a0,g,a1,a1,u
  gll16(a0p0, (char*)&As[0][0] + a0d0);
  gll16(a0p1, (char*)&As[0][0] + a0d1);
  gll16(gp,   (char*)&Bg[0][0] + bd);
  gll16(a1p0, (char*)&As[0][0] + a1d0);
  gll16(a1p1, (char*)&As[0][0] + a1d1);
  gll16(upp,  (char*)&Bu[0][0] + bd);
  a0p0 += BK; a0p1 += BK; a1p0 += BK; a1p1 += BK; gp += BK; upp += BK;

#pragma unroll 1
  for (int t7 = 0; t7 < 7; ++t7) {
    GU_ITER(0, 1);
    GU_ITER(1, 0);
  }
  GU_ITER(0, 1);
  {  // epilogue K-tile (CUR=1; tile 15 fully staged during tile 14)
    bf16x8 af[2][2], af2[2][2], bg2[2][2], bu2[2][2];
    WAITBAR(3);
    LDF(As, 1, wm, af); LDF(Bg, 0, wn, bg2);
    MM8(accg, 0, 0, af, bg2);
    WAITBAR(0);
    LDF(Bu, 0, wn, bu2);
    MM8(accu, 0, 0, af, bu2);
    WAITBAR(0);
    LDF(As, 1, wm + 32, af2);
    MM8(accg, 1, 0, af2, bg2);
    MM8(accu, 1, 0, af2, bu2);
  }
#undef GU_ITER

  const int rq = fq * 4;
#pragma unroll
  for (int mi = 0; mi < 4; ++mi) {
#pragma unroll
    for (int r = 0; r < 4; ++r) {
      int row = m0 + wm + mi * 16 + rq + r;
      if (row < count) {
        unsigned short* h = hidden + (size_t)(base + row) * HS + n0 + wn;
#pragma unroll
        for (int ni = 0; ni < 2; ++ni) {
          float gv = accg[mi][ni][r];
          float uv = accu[mi][ni][r];
          float sig = 1.0f / (1.0f + __expf(-gv));
          h[ni * 16 + fm] = cvt_bf16(gv * sig * uv);
        }
      }
    }
  }
}

// ---------------- GEMM 2 (R5-best): down, scatter rows to out ----------------
// BM=256, BN=128, BK=64, 512 thr (8 waves, 4M x 2N), LDS 96 KiB (dbuf A+B).
// Waits steady 5/5/4; epilogue 3/2/0.
__global__ __launch_bounds__(512) void k_down(
    const unsigned short* __restrict__ hidden,
    const unsigned short* __restrict__ dwt,
    const int* __restrict__ meta,
    const int2* __restrict__ table,
    const int* __restrict__ perm,
    float* __restrict__ out) {
  __shared__ __align__(16) unsigned short As[2][256 * BK];
  __shared__ __align__(16) unsigned short Bs[2][128 * BK];
  const int bid = blockIdx.x, tid = threadIdx.x;
  // XCD-aware swizzle: grid = 8*TBLN = 544 = 8*68 (bijective)
  const int lb = (bid & 7) * (8 * TBLN / 8) + (bid >> 3);
  const int2 te = table[lb >> 3];
  if (te.x < 0) return;
  const int seg = te.x, m0 = te.y;
  const int count = meta[seg], base = meta[5 + seg];
  const int n0 = (lb & 7) * 128;

  const int lane = tid & 63;
  const int wv = tid >> 6;
  const int l0 = lane >> 3, j = lane & 7;

  const int rl0 = wv * 8, rl1 = 64 + wv * 8;
  const int rb0 = (rl0 & 31) + (rl0 >> 5) * 64;
  const int rb1 = (rl1 & 31) + (rl1 >> 5) * 64;
  const int a0d0 = rb0 * 128, a0d1 = rb1 * 128;
  const int a1d0 = a0d0 + 32 * 128, a1d1 = a0d1 + 32 * 128;
  const int r00 = rb0 + l0, r01 = rb1 + l0;
  const int r10 = r00 + 32, r11 = r01 + 32;
  auto rowof = [&](int r) { int g = m0 + r; return g < count ? g : count - 1; };
  const unsigned short* a0p0 = hidden + (size_t)(base + rowof(r00)) * HS + (j ^ (r00 & 7)) * 8;
  const unsigned short* a0p1 = hidden + (size_t)(base + rowof(r01)) * HS + (j ^ (r01 & 7)) * 8;
  const unsigned short* a1p0 = hidden + (size_t)(base + rowof(r10)) * HS + (j ^ (r10 & 7)) * 8;
  const unsigned short* a1p1 = hidden + (size_t)(base + rowof(r11)) * HS + (j ^ (r11 & 7)) * 8;
  const int nl = wv * 8 + l0;                      // 0..63
  const int nb0 = (nl & 31) + (nl >> 5) * 64;      // B stripe rows (nh0)
  const int nb1 = nb0 + 32;
  const unsigned short* bp0 = dwt + (size_t)(seg * DM + n0 + nb0) * HS + (j ^ (nb0 & 7)) * 8;
  const unsigned short* bp1 = dwt + (size_t)(seg * DM + n0 + nb1) * HS + (j ^ (nb1 & 7)) * 8;
  const int bw = wv * 8;
  const int bd0 = ((bw & 31) + (bw >> 5) * 64) * 128;
  const int bd1 = bd0 + 32 * 128;

  const int wm = (wv & 3) * 64;          // 4 M-waves
  const int wn = (wv >> 2) * 64;         // 2 N-waves
  const int fm = lane & 15, fq = lane >> 4;
  const int x0 = (fq ^ (fm & 7)) * 8;
  const int x1 = ((4 + fq) ^ (fm & 7)) * 8;

  f32x4 acc[4][4] = {};

#define DN_ITER(CUR, NXT) {                                   \
    bf16x8 af[2][2], af2[2][2], b0[2][2], b1[2][2];           \
    gll16(a0p0, (char*)&As[NXT][0] + a0d0);                   \
    gll16(a0p1, (char*)&As[NXT][0] + a0d1);                   \
    WAITBAR(5);                                               \
    LDF(As, CUR, wm, af); LDF(Bs, CUR, wn, b0);               \
    MM8(acc, 0, 0, af, b0);                                   \
    gll16(bp0, (char*)&Bs[NXT][0] + bd0);                     \
    WAITBAR(5);                                               \
    LDF(Bs, CUR, wn + 32, b1);                                \
    MM8(acc, 0, 1, af, b1);                                   \
    gll16(bp1, (char*)&Bs[NXT][0] + bd1);                     \
    WAITBAR(4);                                               \
    LDF(As, CUR, wm + 32, af2);                               \
    MM8(acc, 1, 0, af2, b0);                                  \
    gll16(a1p0, (char*)&As[NXT][0] + a1d0);                   \
    gll16(a1p1, (char*)&As[NXT][0] + a1d1);                   \
    MM8(acc, 1, 1, af2, b1);                                  \
    a0p0 += BK; a0p1 += BK; a1p0 += BK; a1p1 += BK; bp0 += BK; bp1 += BK; \
  }

  // prologue: stage tile 0, slot order s0,s1,s2,s3
  gll16(a0p0, (char*)&As[0][0] + a0d0);
  gll16(a0p1, (char*)&As[0][0] + a0d1);
  gll16(bp0,  (char*)&Bs[0][0] + bd0);
  gll16(bp1,  (char*)&Bs[0][0] + bd1);
  gll16(a1p0, (char*)&As[0][0] + a1d0);
  gll16(a1p1, (char*)&As[0][0] + a1d1);
  a0p0 += BK; a0p1 += BK; a1p0 += BK; a1p1 += BK; bp0 += BK; bp1 += BK;

#pragma unroll 1
  for (int t7 = 0; t7 < 7; ++t7) {
    DN_ITER(0, 1);
    DN_ITER(1, 0);
  }
  DN_ITER(0, 1);
  {  // epilogue K-tile (CUR=1)
    bf16x8 af[2][2], af2[2][2], b0[2][2], b1[2][2];
    WAITBAR(3);
    LDF(As, 1, wm, af); LDF(Bs, 1, wn, b0);
    MM8(acc, 0, 0, af, b0);
    WAITBAR(2);
    LDF(Bs, 1, wn + 32, b1);
    MM8(acc, 0, 1, af, b1);
    WAITBAR(0);
    LDF(As, 1, wm + 32, af2);
    MM8(acc, 1, 0, af2, b0);
    MM8(acc, 1, 1, af2, b1);
  }
#undef DN_ITER

  const int rq = fq * 4;
#pragma unroll
  for (int mi = 0; mi < 4; ++mi) {
#pragma unroll
    for (int r = 0; r < 4; ++r) {
      int row = m0 + wm + mi * 16 + rq + r;
      if (row < count) {
        int t = perm[base + row];
        float* o = out + (size_t)t * DM + n0 + wn;
#pragma unroll
        for (int ni = 0; ni < 4; ++ni)
          o[ni * 16 + fm] = acc[mi][ni][r];
      }
    }
  }
}

// ---------------- launch ----------------

extern "C" void kernel_launch(void* const* d_in, const int* in_sizes, int n_in,
                              void* d_out, int out_size, void* d_ws, size_t ws_size,
                              hipStream_t stream) {
  const float* x  = (const float*)d_in[0];
  const float* gw = (const float*)d_in[1];
  const float* uw = (const float*)d_in[2];
  const float* dw = (const float*)d_in[3];
  const int* tsi  = (const int*)d_in[4];
  float* out = (float*)d_out;

  char* ws = (char*)d_ws;
  int*  meta  = (int*)ws;                        // 64 ints
  int*  part  = (int*)(ws + 256);                // 64*8 ints
  int2* table = (int2*)(ws + 4096);              // TBLN entries
  int*  perm  = (int*)(ws + 8192);               // NT ints (64 KiB)
  unsigned short* xc  = (unsigned short*)(ws + (1 << 18));  // 32 MiB compacted
  unsigned short* gwt = xc + (size_t)NT * DM;               // 8 MiB
  unsigned short* uwt = gwt + (size_t)NSEG * HS * DM;       // 8 MiB
  unsigned short* dwt = uwt + (size_t)NSEG * HS * DM;       // 8 MiB
  unsigned short* hid = dwt + (size_t)NSEG * DM * HS;       // 32 MiB compacted

  k_scan<<<64, 256, 0, stream>>>(tsi, part);
  k_prep<<<2048 + 3072, 256, 0, stream>>>(tsi, part, (const float4*)x, meta, table,
                                          perm, (uint4*)xc, gw, uw, dw, gwt, uwt, dwt);
  k_gateup<<<16 * TBLN, 512, 0, stream>>>(xc, gwt, uwt, meta, table, hid);
  k_down<<<8 * TBLN, 512, 0, stream>>>(hid, dwt, meta, table, perm, out);
}